// Round 4
// baseline (636.748 us; speedup 1.0000x reference)
//
#include <hip/hip_runtime.h>
#include <stdint.h>

// RzLinear: out[M,N] = x[M,K] @ W[K,N] + bias, W[k,n] = table[((k*r3+n*r2+r1)%P)%H]
// Phase 1 (uniform prep): every block converts a 2048-float x-chunk AND
//   gather-builds a 1024-elem Wt slice (4 gathers/thread, latency hidden
//   under the streaming cvt). nt on all streams; table stays L2-cached.
// Phase 2: 256x256 MFMA GEMM, BK=64 K-tiles split into two k-halves,
//   m201-style 4 phases/K-tile: {reads, stage half, barrier, lgkm(0),
//   setprio+16 MFMA, barrier}, counted vmcnt(4)/vmcnt(8) — never 0 mid-loop.

#define P_CONST 56598313u
#define HASH_MASK 0xFFFFFu
#define M_DIM 8192
#define N_DIM 4096
#define K_DIM 4096
#define KT (K_DIM / 64)  // 64 K-tiles of 64

typedef __attribute__((ext_vector_type(8))) short bf16x8;
typedef __attribute__((ext_vector_type(4))) float f32x4;
typedef __attribute__((ext_vector_type(4))) unsigned int u32x4;
typedef __attribute__((ext_vector_type(2))) unsigned int u32x2;

__device__ __forceinline__ unsigned short f2bf(float f) {
    unsigned int u = __float_as_uint(f);
    return (unsigned short)((u + 0x7FFFu + ((u >> 16) & 1u)) >> 16);  // RNE
}

struct RN { unsigned long long r1, r2, r3; };

// random_numbers = [P, r1, r2, r3]; reference dtype is int64 but hedge for int32.
__device__ __forceinline__ RN decode_rn(const void* rn_raw) {
    RN o;
    const long long* rn64 = (const long long*)rn_raw;
    if (rn64[0] == 56598313LL) {
        o.r1 = (unsigned long long)rn64[1];
        o.r2 = (unsigned long long)rn64[2];
        o.r3 = (unsigned long long)rn64[3];
    } else {
        const int* rn32 = (const int*)rn_raw;
        o.r1 = (unsigned long long)(unsigned int)rn32[1];
        o.r2 = (unsigned long long)(unsigned int)rn32[2];
        o.r3 = (unsigned long long)(unsigned int)rn32[3];
    }
    return o;
}

// direct global->LDS, 16B per lane (wave-uniform LDS base + lane*16)
__device__ __forceinline__ void load16(const void* g, void* l) {
    __builtin_amdgcn_global_load_lds(
        (const __attribute__((address_space(1))) void*)g,
        (__attribute__((address_space(3))) void*)l,
        16, 0, 0);
}

// ---------------- Phase 1: uniform fused prep (16384 blocks) ----------------
// Every block: gather slice (n = b>>2, k = (b&3)*1024 + t*4, 4 elems/thread)
// + cvt slice (2048 floats of x). Gather loads issued first so their L2
// latency hides under the cvt streaming.
__global__ __launch_bounds__(256) void prep(const float* __restrict__ x,
                                            const float* __restrict__ table,
                                            const void* __restrict__ rn_raw,
                                            unsigned short* __restrict__ Wt,
                                            unsigned short* __restrict__ Xb) {
    const int b = blockIdx.x;
    const int t = threadIdx.x;
    // ---- gather address setup + issue 4 table loads ----
    RN rn = decode_rn(rn_raw);
    const unsigned int stepu = (unsigned int)(rn.r3 % P_CONST);
    const unsigned int n = (unsigned int)(b >> 2);
    const int kb = ((b & 3) << 10) + (t << 2);
    const unsigned long long base =
        ((unsigned long long)n * rn.r2 + rn.r1) % P_CONST;
    unsigned int cur =
        (unsigned int)((base + (unsigned long long)kb * stepu) % P_CONST);
    const float g0 = table[cur & HASH_MASK];
    cur += stepu; if (cur >= P_CONST) cur -= P_CONST;
    const float g1 = table[cur & HASH_MASK];
    cur += stepu; if (cur >= P_CONST) cur -= P_CONST;
    const float g2 = table[cur & HASH_MASK];
    cur += stepu; if (cur >= P_CONST) cur -= P_CONST;
    const float g3 = table[cur & HASH_MASK];
    // ---- cvt slice (streams while gathers are in flight) ----
    const size_t i8 = ((size_t)b * 256 + t) * 8;
    const f32x4 a = __builtin_nontemporal_load((const f32x4*)(x + i8));
    const f32x4 c = __builtin_nontemporal_load((const f32x4*)(x + i8 + 4));
    union { unsigned short s[8]; u32x4 v; } o;
    o.s[0] = f2bf(a.x); o.s[1] = f2bf(a.y); o.s[2] = f2bf(a.z); o.s[3] = f2bf(a.w);
    o.s[4] = f2bf(c.x); o.s[5] = f2bf(c.y); o.s[6] = f2bf(c.z); o.s[7] = f2bf(c.w);
    __builtin_nontemporal_store(o.v, (u32x4*)(Xb + i8));
    // ---- finish gather: pack 4 bf16 (8B coalesced store per lane) ----
    union { unsigned short s[4]; u32x2 v; } w;
    w.s[0] = f2bf(g0); w.s[1] = f2bf(g1); w.s[2] = f2bf(g2); w.s[3] = f2bf(g3);
    __builtin_nontemporal_store(w.v, (u32x2*)(Wt + (size_t)n * K_DIM + kb));
}

// ---------------- Phase 2: 256x256 GEMM, BK=64, 4 phases/K-tile ----------------
// A: [M][K] bf16 row-major, Bt: [N][K] bf16 row-major.
// 8 waves (2 M x 4 N), per-wave 128x64 C-tile. K-tile = 64, split into two
// k-halves (kh) of 32 elems => 64-B LDS rows, [2 dbuf][2 kh][256*32] per matrix.
// Phases per tile: ph0 {af[8] kh0 + B n01 kh0; stage klow(t+1); 16 MFMA},
// ph1 {B n23 kh0; stage khigh(t+1); 16 MFMA; vmcnt(8)}, ph2 {af[8] kh1 +
// B n01 kh1; 16 MFMA}, ph3 {B n23 kh1; 16 MFMA; vmcnt(4)}.
// Wait math (4 loads/half-tile/thread): before ph0-reads, outstanding = 8
// (klow(t)+khigh(t)), vmcnt(4) retires klow(t); before ph2-reads,
// outstanding = 12, vmcnt(8) retires khigh(t). Each vmcnt precedes a barrier
// => collective landing guarantee. Never drains to 0 except the tail.
// LDS swizzle (64-B rows): slot ^= (row>>1)&3, via pre-swizzled global source
// (p ^ ((p>>3)&0x30)) and qswz = (q ^ ((lm>>1)&3))<<4 on ds_read (2-way max).
__global__ __launch_bounds__(512, 2) void gemm_bt64(
    const unsigned short* __restrict__ A,
    const unsigned short* __restrict__ Bt,
    const float* __restrict__ bias,
    float* __restrict__ C) {
    __shared__ __align__(16) unsigned short lA[2][2][256 * 32];  // 64 KiB
    __shared__ __align__(16) unsigned short lB[2][2][256 * 32];  // 64 KiB

    const int t = threadIdx.x;
    // bijective XCD swizzle: 512 blocks = 8 XCDs x 64
    const int bid0 = blockIdx.x;
    const int sb = (bid0 & 7) * 64 + (bid0 >> 3);
    const int m0 = (sb >> 4) * 256;  // 32 m-tiles
    const int n0 = (sb & 15) * 256;  // 16 n-tiles

    const int lane = t & 63;
    const int wid = t >> 6;
    const int wr = wid >> 2;  // 0..1 -> C rows wr*128..+127
    const int wc = wid & 3;   // 0..3 -> C cols wc*64..+63
    const int lm = lane & 15;
    const int q = lane >> 4;  // 16B k-slot within 64-B row
    const int qswz = (q ^ ((lm >> 1) & 3)) << 4;

    // staging geometry: thread t owns LDS bytes p0=t*16, p1=p0+8192 of each
    // 16 KiB half-tile; global source pre-swizzled (involution on bits 4-5).
    const int p0 = t * 16;
    const int p1 = p0 + 8192;
    const int l0 = p0 ^ ((p0 >> 3) & 0x30);
    const int l1 = p1 ^ ((p1 >> 3) & 0x30);
    const int r0 = l0 >> 6, c0 = (l0 & 63) >> 1;  // row 0..127, col elems 0..31
    const int r1 = l1 >> 6, c1 = (l1 & 63) >> 1;  // row 128..255

    const unsigned short* Abase = A + (size_t)m0 * K_DIM;
    const unsigned short* Bbase = Bt + (size_t)n0 * K_DIM;

    f32x4 acc[8][4] = {};

    // stage one k-half of tile T (A + B, 4 loads/thread)
#define STAGE(T, KH) do {                                                       \
    const int db__ = (T) & 1;                                                   \
    const size_t ko__ = (size_t)(T) * 64 + (KH) * 32;                           \
    load16(Abase + (size_t)r0 * K_DIM + ko__ + c0, (char*)&lA[db__][KH][0] + p0);\
    load16(Abase + (size_t)r1 * K_DIM + ko__ + c1, (char*)&lA[db__][KH][0] + p1);\
    load16(Bbase + (size_t)r0 * K_DIM + ko__ + c0, (char*)&lB[db__][KH][0] + p0);\
    load16(Bbase + (size_t)r1 * K_DIM + ko__ + c1, (char*)&lB[db__][KH][0] + p1);\
} while (0)

#define MFMA16(JB) do {                                                         \
    _Pragma("unroll")                                                           \
    for (int i = 0; i < 8; ++i) {                                               \
        acc[i][JB] = __builtin_amdgcn_mfma_f32_16x16x32_bf16(                   \
            af[i], bq0, acc[i][JB], 0, 0, 0);                                   \
        acc[i][(JB) + 1] = __builtin_amdgcn_mfma_f32_16x16x32_bf16(             \
            af[i], bq1, acc[i][(JB) + 1], 0, 0, 0);                             \
    }                                                                           \
} while (0)

#define BAR() do { __builtin_amdgcn_s_barrier();                                \
                   asm volatile("" ::: "memory"); } while (0)
#define LGKM0() do { asm volatile("s_waitcnt lgkmcnt(0)" ::: "memory");         \
                     __builtin_amdgcn_sched_barrier(0); } while (0)

    // prologue: stage both halves of tile 0 (8 loads), wait for klow only
    STAGE(0, 0);
    STAGE(0, 1);
    asm volatile("s_waitcnt vmcnt(4)" ::: "memory");
    BAR();

#pragma unroll 1
    for (int tt = 0; tt < KT; ++tt) {
        const int db = tt & 1;
        const char* a0 = (const char*)&lA[db][0][0];
        const char* a1 = (const char*)&lA[db][1][0];
        const char* b0 = (const char*)&lB[db][0][0];
        const char* b1 = (const char*)&lB[db][1][0];
        bf16x8 af[8], bq0, bq1;

        // ---- ph0: kh0, n-subs 0-1 ----
#pragma unroll
        for (int i = 0; i < 8; ++i)
            af[i] = *(const bf16x8*)(a0 + (((wr * 128 + i * 16 + lm) << 6) | qswz));
        bq0 = *(const bf16x8*)(b0 + (((wc * 64 + 0 * 16 + lm) << 6) | qswz));
        bq1 = *(const bf16x8*)(b0 + (((wc * 64 + 1 * 16 + lm) << 6) | qswz));
        if (tt + 1 < KT) STAGE(tt + 1, 0);
        BAR();
        LGKM0();
        __builtin_amdgcn_s_setprio(1);
        MFMA16(0);
        __builtin_amdgcn_s_setprio(0);
        BAR();

        // ---- ph1: kh0, n-subs 2-3 ----
        bq0 = *(const bf16x8*)(b0 + (((wc * 64 + 2 * 16 + lm) << 6) | qswz));
        bq1 = *(const bf16x8*)(b0 + (((wc * 64 + 3 * 16 + lm) << 6) | qswz));
        if (tt + 1 < KT) STAGE(tt + 1, 1);
        BAR();
        LGKM0();
        __builtin_amdgcn_s_setprio(1);
        MFMA16(2);
        __builtin_amdgcn_s_setprio(0);
        // guard ph2's khigh(tt) reads: retire its 4 loads, keep 8 in flight
        if (tt == KT - 1) asm volatile("s_waitcnt vmcnt(0)" ::: "memory");
        else              asm volatile("s_waitcnt vmcnt(8)" ::: "memory");
        BAR();

        // ---- ph2: kh1, n-subs 0-1 ----
#pragma unroll
        for (int i = 0; i < 8; ++i)
            af[i] = *(const bf16x8*)(a1 + (((wr * 128 + i * 16 + lm) << 6) | qswz));
        bq0 = *(const bf16x8*)(b1 + (((wc * 64 + 0 * 16 + lm) << 6) | qswz));
        bq1 = *(const bf16x8*)(b1 + (((wc * 64 + 1 * 16 + lm) << 6) | qswz));
        BAR();
        LGKM0();
        __builtin_amdgcn_s_setprio(1);
        MFMA16(0);
        __builtin_amdgcn_s_setprio(0);
        BAR();

        // ---- ph3: kh1, n-subs 2-3 ----
        bq0 = *(const bf16x8*)(b1 + (((wc * 64 + 2 * 16 + lm) << 6) | qswz));
        bq1 = *(const bf16x8*)(b1 + (((wc * 64 + 3 * 16 + lm) << 6) | qswz));
        BAR();
        LGKM0();
        __builtin_amdgcn_s_setprio(1);
        MFMA16(2);
        __builtin_amdgcn_s_setprio(0);
        // guard next tile's klow reads: retire klow(tt+1), keep khigh(tt+1)
        asm volatile("s_waitcnt vmcnt(4)" ::: "memory");
        BAR();
    }

#undef STAGE
#undef MFMA16
#undef BAR
#undef LGKM0

    // epilogue: C/D layout col=lane&15, row=(lane>>4)*4+reg; nt stores.
#pragma unroll
    for (int j = 0; j < 4; ++j) {
        const int col = n0 + wc * 64 + j * 16 + lm;
        const float bv = bias[col];
#pragma unroll
        for (int i = 0; i < 8; ++i) {
            const int row = m0 + wr * 128 + i * 16 + q * 4;
#pragma unroll
            for (int r = 0; r < 4; ++r)
                __builtin_nontemporal_store(
                    acc[i][j][r] + bv, &C[(size_t)(row + r) * N_DIM + col]);
        }
    }
}

// ---------------- Fallback: fused gather GEMM, zero workspace ----------------
__global__ __launch_bounds__(256) void gemm_fused(const float* __restrict__ X,
                                                  const float* __restrict__ table,
                                                  const void* __restrict__ rn_raw,
                                                  const float* __restrict__ bias,
                                                  float* __restrict__ C) {
    RN rn = decode_rn(rn_raw);
    const unsigned int stepu = (unsigned int)(rn.r3 % P_CONST);
    const unsigned int step32 =
        (unsigned int)(((unsigned long long)stepu * 32ull) % P_CONST);

    __shared__ __align__(16) unsigned short lA[128 * 32];
    __shared__ __align__(16) unsigned short lB[128 * 32];
    const int t = threadIdx.x;
    const int m0 = blockIdx.y * 128;
    const int n0 = blockIdx.x * 128;
    const int lane = t & 63;
    const int w = t >> 6;
    const int wr = w >> 1, wc = w & 1;
    const int lm = lane & 15, q = lane >> 4;

    unsigned int curB[2];
    int rowB[2], colB[2];
#pragma unroll
    for (int e = 0; e < 2; ++e) {
        const int c = t + e * 256;
        rowB[e] = c >> 2;
        colB[e] = (c & 3) * 8;
        const unsigned long long base =
            ((unsigned long long)(n0 + rowB[e]) * rn.r2 + rn.r1) % P_CONST;
        curB[e] =
            (unsigned int)((base + (unsigned long long)colB[e] * stepu) % P_CONST);
    }

    f32x4 acc[4][4] = {};

    for (int k0 = 0; k0 < K_DIM; k0 += 32) {
#pragma unroll
        for (int c = t; c < 1024; c += 256) {
            const int row = c >> 3, col = (c & 7) * 4;
            const float4 v =
                *(const float4*)(X + (size_t)(m0 + row) * K_DIM + k0 + col);
            ushort4 o;
            o.x = f2bf(v.x); o.y = f2bf(v.y); o.z = f2bf(v.z); o.w = f2bf(v.w);
            *(ushort4*)&lA[row * 32 + col] = o;
        }
#pragma unroll
        for (int e = 0; e < 2; ++e) {
            unsigned int cur = curB[e];
            union { unsigned short s[8]; uint4 v; } o;
#pragma unroll
            for (int i = 0; i < 8; ++i) {
                o.s[i] = f2bf(table[cur & HASH_MASK]);
                cur += stepu;
                if (cur >= P_CONST) cur -= P_CONST;
            }
            curB[e] += step32;
            if (curB[e] >= P_CONST) curB[e] -= P_CONST;
            *(uint4*)&lB[rowB[e] * 32 + colB[e]] = o.v;
        }
        __syncthreads();

        bf16x8 af[4], bfr[4];
#pragma unroll
        for (int i = 0; i < 4; ++i)
            af[i] = *(const bf16x8*)&lA[(wr * 64 + i * 16 + lm) * 32 + q * 8];
#pragma unroll
        for (int j = 0; j < 4; ++j)
            bfr[j] = *(const bf16x8*)&lB[(wc * 64 + j * 16 + lm) * 32 + q * 8];
#pragma unroll
        for (int i = 0; i < 4; ++i)
#pragma unroll
            for (int j = 0; j < 4; ++j)
                acc[i][j] = __builtin_amdgcn_mfma_f32_16x16x32_bf16(
                    af[i], bfr[j], acc[i][j], 0, 0, 0);
        __syncthreads();
    }

#pragma unroll
    for (int j = 0; j < 4; ++j) {
        const int col = n0 + wc * 64 + j * 16 + lm;
        const float bv = bias[col];
#pragma unroll
        for (int i = 0; i < 4; ++i) {
            const int row = m0 + wr * 64 + i * 16 + q * 4;
#pragma unroll
            for (int r = 0; r < 4; ++r)
                C[(size_t)(row + r) * N_DIM + col] = acc[i][j][r] + bv;
        }
    }
}

extern "C" void kernel_launch(void* const* d_in, const int* in_sizes, int n_in,
                              void* d_out, int out_size, void* d_ws, size_t ws_size,
                              hipStream_t stream) {
    const float* x = (const float*)d_in[0];
    const float* hw = (const float*)d_in[1];
    const void* rn = d_in[2];
    const float* bias = (const float*)d_in[3];
    float* out = (float*)d_out;

    const size_t wt_bytes = (size_t)N_DIM * K_DIM * 2;  // 32 MB
    const size_t xb_bytes = (size_t)M_DIM * K_DIM * 2;  // 64 MB

    if (ws_size >= wt_bytes + xb_bytes) {
        unsigned short* Wt = (unsigned short*)d_ws;
        unsigned short* Xb = (unsigned short*)((char*)d_ws + wt_bytes);
        prep<<<16384, 256, 0, stream>>>(x, hw, rn, Wt, Xb);
        gemm_bt64<<<dim3((M_DIM / 256) * (N_DIM / 256)), 512, 0, stream>>>(Xb, Wt, bias, out);
    } else {
        gemm_fused<<<dim3(N_DIM / 128, M_DIM / 128), 256, 0, stream>>>(x, hw, rn, bias, out);
    }
}

// Round 5
// 571.081 us; speedup vs baseline: 1.1150x; 1.1150x over previous
//
#include <hip/hip_runtime.h>
#include <stdint.h>

// RzLinear: out[M,N] = x[M,K] @ W[K,N] + bias, W[k,n] = table[((k*r3+n*r2+r1)%P)%H]
// Phase 0: cvt_tbl — convert 1M-entry f32 table to bf16 (2 MB, L2-resident).
// Phase 1: prep — every block converts a 2048-float x-chunk AND gathers a
//   1024-elem Wt slice from the bf16 table (4 gathers/thread; gather loads
//   issued first so latency hides under the streaming cvt). Streams are nt;
//   table loads default-cached so the 2 MB table stays hot per-XCD.
// Phase 2: gemm_bt8 — R1-proven 256x256 MFMA GEMM: ring-of-4 LDS K-step
//   buffers (BK=32), 2 barriers/step, counted vmcnt(8), swizzled LDS, setprio.
//   Measured 268 us / MfmaUtil 47.5 / bank-conflicts 0 — do not restructure
//   (R3 merged-barrier and R4 4-phase variants both regressed).

#define P_CONST 56598313u
#define HASH_MASK 0xFFFFFu
#define M_DIM 8192
#define N_DIM 4096
#define K_DIM 4096
#define BK 32
#define KSTEPS (K_DIM / BK)  // 128

typedef __attribute__((ext_vector_type(8))) short bf16x8;
typedef __attribute__((ext_vector_type(4))) float f32x4;
typedef __attribute__((ext_vector_type(4))) unsigned int u32x4;
typedef __attribute__((ext_vector_type(2))) unsigned int u32x2;

__device__ __forceinline__ unsigned short f2bf(float f) {
    unsigned int u = __float_as_uint(f);
    return (unsigned short)((u + 0x7FFFu + ((u >> 16) & 1u)) >> 16);  // RNE
}

struct RN { unsigned long long r1, r2, r3; };

// random_numbers = [P, r1, r2, r3]; reference dtype is int64 but hedge for int32.
__device__ __forceinline__ RN decode_rn(const void* rn_raw) {
    RN o;
    const long long* rn64 = (const long long*)rn_raw;
    if (rn64[0] == 56598313LL) {
        o.r1 = (unsigned long long)rn64[1];
        o.r2 = (unsigned long long)rn64[2];
        o.r3 = (unsigned long long)rn64[3];
    } else {
        const int* rn32 = (const int*)rn_raw;
        o.r1 = (unsigned long long)(unsigned int)rn32[1];
        o.r2 = (unsigned long long)(unsigned int)rn32[2];
        o.r3 = (unsigned long long)(unsigned int)rn32[3];
    }
    return o;
}

// direct global->LDS, 16B per lane (wave-uniform LDS base + lane*16)
__device__ __forceinline__ void load16(const void* g, void* l) {
    __builtin_amdgcn_global_load_lds(
        (const __attribute__((address_space(1))) void*)g,
        (__attribute__((address_space(3))) void*)l,
        16, 0, 0);
}

// ---------------- Phase 0: table f32 -> bf16 (1M entries) ----------------
__global__ __launch_bounds__(256) void cvt_tbl(const float* __restrict__ table,
                                               unsigned short* __restrict__ tb) {
    const size_t i8 = ((size_t)blockIdx.x * 256 + threadIdx.x) * 8;
    const f32x4 a = *(const f32x4*)(table + i8);
    const f32x4 c = *(const f32x4*)(table + i8 + 4);
    union { unsigned short s[8]; u32x4 v; } o;
    o.s[0] = f2bf(a.x); o.s[1] = f2bf(a.y); o.s[2] = f2bf(a.z); o.s[3] = f2bf(a.w);
    o.s[4] = f2bf(c.x); o.s[5] = f2bf(c.y); o.s[6] = f2bf(c.z); o.s[7] = f2bf(c.w);
    *(u32x4*)(tb + i8) = o.v;  // default caching: we want it resident
}

// ---------------- Phase 1: uniform fused prep (16384 blocks) ----------------
// Gather slice: n = b>>2, k = (b&3)*1024 + t*4 (4 bf16 gathers/thread).
// Cvt slice: 2048 floats of x. Gathers issued first; cvt streams under them.
__global__ __launch_bounds__(256) void prep_bf(const float* __restrict__ x,
                                               const unsigned short* __restrict__ tb,
                                               const void* __restrict__ rn_raw,
                                               unsigned short* __restrict__ Wt,
                                               unsigned short* __restrict__ Xb) {
    const int b = blockIdx.x;
    const int t = threadIdx.x;
    RN rn = decode_rn(rn_raw);
    const unsigned int stepu = (unsigned int)(rn.r3 % P_CONST);
    const unsigned int n = (unsigned int)(b >> 2);
    const int kb = ((b & 3) << 10) + (t << 2);
    const unsigned long long base =
        ((unsigned long long)n * rn.r2 + rn.r1) % P_CONST;
    unsigned int cur =
        (unsigned int)((base + (unsigned long long)kb * stepu) % P_CONST);
    const unsigned int i0 = cur & HASH_MASK;
    cur += stepu; if (cur >= P_CONST) cur -= P_CONST;
    const unsigned int i1 = cur & HASH_MASK;
    cur += stepu; if (cur >= P_CONST) cur -= P_CONST;
    const unsigned int i2 = cur & HASH_MASK;
    cur += stepu; if (cur >= P_CONST) cur -= P_CONST;
    const unsigned int i3 = cur & HASH_MASK;
    const unsigned short g0 = tb[i0];  // bf16 gathers, default-cached
    const unsigned short g1 = tb[i1];
    const unsigned short g2 = tb[i2];
    const unsigned short g3 = tb[i3];
    // ---- cvt slice (streams while gathers are in flight) ----
    const size_t i8 = ((size_t)b * 256 + t) * 8;
    const f32x4 a = __builtin_nontemporal_load((const f32x4*)(x + i8));
    const f32x4 c = __builtin_nontemporal_load((const f32x4*)(x + i8 + 4));
    union { unsigned short s[8]; u32x4 v; } o;
    o.s[0] = f2bf(a.x); o.s[1] = f2bf(a.y); o.s[2] = f2bf(a.z); o.s[3] = f2bf(a.w);
    o.s[4] = f2bf(c.x); o.s[5] = f2bf(c.y); o.s[6] = f2bf(c.z); o.s[7] = f2bf(c.w);
    __builtin_nontemporal_store(o.v, (u32x4*)(Xb + i8));
    // ---- finish gather: 8B coalesced store per lane ----
    union { unsigned short s[4]; u32x2 v; } w;
    w.s[0] = g0; w.s[1] = g1; w.s[2] = g2; w.s[3] = g3;
    __builtin_nontemporal_store(w.v, (u32x2*)(Wt + (size_t)n * K_DIM + kb));
}

// Fallback prep if ws can't fit the bf16 table: gather f32 directly.
__global__ __launch_bounds__(256) void prep_f32(const float* __restrict__ x,
                                                const float* __restrict__ table,
                                                const void* __restrict__ rn_raw,
                                                unsigned short* __restrict__ Wt,
                                                unsigned short* __restrict__ Xb) {
    const int b = blockIdx.x;
    const int t = threadIdx.x;
    RN rn = decode_rn(rn_raw);
    const unsigned int stepu = (unsigned int)(rn.r3 % P_CONST);
    const unsigned int n = (unsigned int)(b >> 2);
    const int kb = ((b & 3) << 10) + (t << 2);
    const unsigned long long base =
        ((unsigned long long)n * rn.r2 + rn.r1) % P_CONST;
    unsigned int cur =
        (unsigned int)((base + (unsigned long long)kb * stepu) % P_CONST);
    const float g0 = table[cur & HASH_MASK];
    cur += stepu; if (cur >= P_CONST) cur -= P_CONST;
    const float g1 = table[cur & HASH_MASK];
    cur += stepu; if (cur >= P_CONST) cur -= P_CONST;
    const float g2 = table[cur & HASH_MASK];
    cur += stepu; if (cur >= P_CONST) cur -= P_CONST;
    const float g3 = table[cur & HASH_MASK];
    const size_t i8 = ((size_t)b * 256 + t) * 8;
    const f32x4 a = __builtin_nontemporal_load((const f32x4*)(x + i8));
    const f32x4 c = __builtin_nontemporal_load((const f32x4*)(x + i8 + 4));
    union { unsigned short s[8]; u32x4 v; } o;
    o.s[0] = f2bf(a.x); o.s[1] = f2bf(a.y); o.s[2] = f2bf(a.z); o.s[3] = f2bf(a.w);
    o.s[4] = f2bf(c.x); o.s[5] = f2bf(c.y); o.s[6] = f2bf(c.z); o.s[7] = f2bf(c.w);
    __builtin_nontemporal_store(o.v, (u32x4*)(Xb + i8));
    union { unsigned short s[4]; u32x2 v; } w;
    w.s[0] = f2bf(g0); w.s[1] = f2bf(g1); w.s[2] = f2bf(g2); w.s[3] = f2bf(g3);
    __builtin_nontemporal_store(w.v, (u32x2*)(Wt + (size_t)n * K_DIM + kb));
}

// ---------------- Phase 2: 256x256 pipelined GEMM (R1-proven) ----------------
// A: [M][K] bf16 row-major, Bt: [N][K] bf16 row-major.
// 8 waves (2 M x 4 N), per-wave 128x64 C-tile, BK=32, ring of 4 K-step buffers.
// Staging runs 3 steps ahead; vmcnt(8) per step (2 steps in flight, never 0).
// LDS swizzle: involution p ^= ((p>>3)&0x30) on the GLOBAL source (LDS dest
// linear, per global_load_lds rules) and on the ds_read address.
__global__ __launch_bounds__(512, 2) void gemm_bt8(
    const unsigned short* __restrict__ A,
    const unsigned short* __restrict__ Bt,
    const float* __restrict__ bias,
    float* __restrict__ C) {
    __shared__ __align__(16) unsigned short lA[4][256 * BK];  // 4 x 16 KiB
    __shared__ __align__(16) unsigned short lB[4][256 * BK];  // 4 x 16 KiB

    const int t = threadIdx.x;
    // bijective XCD swizzle: 512 blocks = 8 XCDs x 64
    const int bid0 = blockIdx.x;
    const int sb = (bid0 & 7) * 64 + (bid0 >> 3);
    const int m0 = (sb >> 4) * 256;  // 32 m-tiles
    const int n0 = (sb & 15) * 256;  // 16 n-tiles

    const int lane = t & 63;
    const int wid = t >> 6;
    const int wr = wid >> 2;  // 0..1 -> C rows wr*128..+127
    const int wc = wid & 3;   // 0..3 -> C cols wc*64..+63
    const int lm = lane & 15;
    const int q = lane >> 4;  // 0..3 (16B k-slot)
    // swizzled 16B slot within a 64B LDS row (2-way aliasing only = free)
    const int qswz = (q ^ ((lm >> 1) & 3)) << 4;

    // staging geometry: thread t owns LDS bytes p0=t*16 and p1=p0+8192; global
    // source pre-swizzled so the ds_read side can swizzle.
    const int p0 = t * 16;
    const int p1 = p0 + 8192;
    const int l0 = p0 ^ ((p0 >> 3) & 0x30);
    const int l1 = p1 ^ ((p1 >> 3) & 0x30);
    const int r0 = l0 >> 6, c0 = (l0 & 63) >> 1;  // row 0..127, col (elems)
    const int r1 = l1 >> 6, c1 = (l1 & 63) >> 1;  // row 128..255

    const unsigned short* Abase = A + (size_t)m0 * K_DIM;
    const unsigned short* Bbase = Bt + (size_t)n0 * K_DIM;

    f32x4 acc[8][4] = {};

#define STAGE_A(KS) do { const int b__ = (KS) & 3;                              \
    load16(Abase + (size_t)r0 * K_DIM + (KS) * BK + c0, (char*)&lA[b__][0] + p0);\
    load16(Abase + (size_t)r1 * K_DIM + (KS) * BK + c1, (char*)&lA[b__][0] + p1);\
} while (0)
#define STAGE_B(KS) do { const int b__ = (KS) & 3;                              \
    load16(Bbase + (size_t)r0 * K_DIM + (KS) * BK + c0, (char*)&lB[b__][0] + p0);\
    load16(Bbase + (size_t)r1 * K_DIM + (KS) * BK + c1, (char*)&lB[b__][0] + p1);\
} while (0)

    // Per step: top barrier (own vmcnt + barrier => whole tile landed).
    // phase0: read 4 A-frags + 4 B-frags, issue next A stage, 16 MFMA.
    // phase1: read 4 A-frags, issue next B stage, 16 MFMA.
    // WAR on ring buffer is safe: issuing wave passed the top barrier, which is
    // after every wave's lgkmcnt(0) of the step that last read that buffer.
#define STEP_BODY(KS, STG) do {                                                 \
    __builtin_amdgcn_s_barrier();                                               \
    asm volatile("" ::: "memory");                                              \
    const char* bufA = (const char*)&lA[(KS) & 3][0];                           \
    const char* bufB = (const char*)&lB[(KS) & 3][0];                           \
    bf16x8 af[4], bfr[4];                                                       \
    _Pragma("unroll")                                                           \
    for (int i = 0; i < 4; ++i)                                                 \
        af[i] = *(const bf16x8*)(bufA + (((wr * 128 + i * 16 + lm) << 6) | qswz));\
    _Pragma("unroll")                                                           \
    for (int j = 0; j < 4; ++j)                                                 \
        bfr[j] = *(const bf16x8*)(bufB + (((wc * 64 + j * 16 + lm) << 6) | qswz));\
    if (STG) STAGE_A((KS) + 3);                                                 \
    asm volatile("s_waitcnt lgkmcnt(0)" ::: "memory");                          \
    __builtin_amdgcn_sched_barrier(0);                                          \
    __builtin_amdgcn_s_setprio(1);                                              \
    _Pragma("unroll")                                                           \
    for (int i = 0; i < 4; ++i)                                                 \
        _Pragma("unroll")                                                       \
        for (int j = 0; j < 4; ++j)                                             \
            acc[i][j] = __builtin_amdgcn_mfma_f32_16x16x32_bf16(                \
                af[i], bfr[j], acc[i][j], 0, 0, 0);                             \
    __builtin_amdgcn_s_setprio(0);                                              \
    __builtin_amdgcn_s_barrier();                                               \
    asm volatile("" ::: "memory");                                              \
    _Pragma("unroll")                                                           \
    for (int i = 0; i < 4; ++i)                                                 \
        af[i] = *(const bf16x8*)(bufA + (((wr * 128 + 64 + i * 16 + lm) << 6) | qswz));\
    if (STG) STAGE_B((KS) + 3);                                                 \
    asm volatile("s_waitcnt lgkmcnt(0)" ::: "memory");                          \
    __builtin_amdgcn_sched_barrier(0);                                          \
    __builtin_amdgcn_s_setprio(1);                                              \
    _Pragma("unroll")                                                           \
    for (int i = 0; i < 4; ++i)                                                 \
        _Pragma("unroll")                                                       \
        for (int j = 0; j < 4; ++j)                                             \
            acc[i + 4][j] = __builtin_amdgcn_mfma_f32_16x16x32_bf16(            \
                af[i], bfr[j], acc[i + 4][j], 0, 0, 0);                         \
    __builtin_amdgcn_s_setprio(0);                                              \
} while (0)

    // prologue: stage steps 0,1,2 (12 loads/thread in flight)
    STAGE_A(0); STAGE_B(0);
    STAGE_A(1); STAGE_B(1);
    STAGE_A(2); STAGE_B(2);

#pragma unroll 1
    for (int ks = 0; ks < KSTEPS - 2; ++ks) {
        // retire step ks's 4 loads; steps ks+1, ks+2 (8 loads) stay in flight
        asm volatile("s_waitcnt vmcnt(8)" ::: "memory");
        STEP_BODY(ks, (ks < KSTEPS - 3));
    }
    asm volatile("s_waitcnt vmcnt(4)" ::: "memory");
    STEP_BODY(KSTEPS - 2, false);
    asm volatile("s_waitcnt vmcnt(0)" ::: "memory");
    STEP_BODY(KSTEPS - 1, false);

#undef STEP_BODY
#undef STAGE_A
#undef STAGE_B

    // epilogue: C/D layout col=lane&15, row=(lane>>4)*4+reg
#pragma unroll
    for (int j = 0; j < 4; ++j) {
        const int col = n0 + wc * 64 + j * 16 + lm;
        const float bv = bias[col];
#pragma unroll
        for (int i = 0; i < 8; ++i) {
            const int row = m0 + wr * 128 + i * 16 + q * 4;
#pragma unroll
            for (int r = 0; r < 4; ++r)
                C[(size_t)(row + r) * N_DIM + col] = acc[i][j][r] + bv;
        }
    }
}

// ---------------- Fallback: fused gather GEMM, zero workspace ----------------
__global__ __launch_bounds__(256) void gemm_fused(const float* __restrict__ X,
                                                  const float* __restrict__ table,
                                                  const void* __restrict__ rn_raw,
                                                  const float* __restrict__ bias,
                                                  float* __restrict__ C) {
    RN rn = decode_rn(rn_raw);
    const unsigned int stepu = (unsigned int)(rn.r3 % P_CONST);
    const unsigned int step32 =
        (unsigned int)(((unsigned long long)stepu * 32ull) % P_CONST);

    __shared__ __align__(16) unsigned short lA[128 * 32];
    __shared__ __align__(16) unsigned short lB[128 * 32];
    const int t = threadIdx.x;
    const int m0 = blockIdx.y * 128;
    const int n0 = blockIdx.x * 128;
    const int lane = t & 63;
    const int w = t >> 6;
    const int wr = w >> 1, wc = w & 1;
    const int lm = lane & 15, q = lane >> 4;

    unsigned int curB[2];
    int rowB[2], colB[2];
#pragma unroll
    for (int e = 0; e < 2; ++e) {
        const int c = t + e * 256;
        rowB[e] = c >> 2;
        colB[e] = (c & 3) * 8;
        const unsigned long long base =
            ((unsigned long long)(n0 + rowB[e]) * rn.r2 + rn.r1) % P_CONST;
        curB[e] =
            (unsigned int)((base + (unsigned long long)colB[e] * stepu) % P_CONST);
    }

    f32x4 acc[4][4] = {};

    for (int k0 = 0; k0 < K_DIM; k0 += 32) {
#pragma unroll
        for (int c = t; c < 1024; c += 256) {
            const int row = c >> 3, col = (c & 7) * 4;
            const float4 v =
                *(const float4*)(X + (size_t)(m0 + row) * K_DIM + k0 + col);
            ushort4 o;
            o.x = f2bf(v.x); o.y = f2bf(v.y); o.z = f2bf(v.z); o.w = f2bf(v.w);
            *(ushort4*)&lA[row * 32 + col] = o;
        }
#pragma unroll
        for (int e = 0; e < 2; ++e) {
            unsigned int cur = curB[e];
            union { unsigned short s[8]; uint4 v; } o;
#pragma unroll
            for (int i = 0; i < 8; ++i) {
                o.s[i] = f2bf(table[cur & HASH_MASK]);
                cur += stepu;
                if (cur >= P_CONST) cur -= P_CONST;
            }
            curB[e] += step32;
            if (curB[e] >= P_CONST) curB[e] -= P_CONST;
            *(uint4*)&lB[rowB[e] * 32 + colB[e]] = o.v;
        }
        __syncthreads();

        bf16x8 af[4], bfr[4];
#pragma unroll
        for (int i = 0; i < 4; ++i)
            af[i] = *(const bf16x8*)&lA[(wr * 64 + i * 16 + lm) * 32 + q * 8];
#pragma unroll
        for (int j = 0; j < 4; ++j)
            bfr[j] = *(const bf16x8*)&lB[(wc * 64 + j * 16 + lm) * 32 + q * 8];
#pragma unroll
        for (int i = 0; i < 4; ++i)
#pragma unroll
            for (int j = 0; j < 4; ++j)
                acc[i][j] = __builtin_amdgcn_mfma_f32_16x16x32_bf16(
                    af[i], bfr[j], acc[i][j], 0, 0, 0);
        __syncthreads();
    }

#pragma unroll
    for (int j = 0; j < 4; ++j) {
        const int col = n0 + wc * 64 + j * 16 + lm;
        const float bv = bias[col];
#pragma unroll
        for (int i = 0; i < 4; ++i) {
            const int row = m0 + wr * 64 + i * 16 + q * 4;
#pragma unroll
            for (int r = 0; r < 4; ++r)
                C[(size_t)(row + r) * N_DIM + col] = acc[i][j][r] + bv;
        }
    }
}

extern "C" void kernel_launch(void* const* d_in, const int* in_sizes, int n_in,
                              void* d_out, int out_size, void* d_ws, size_t ws_size,
                              hipStream_t stream) {
    const float* x = (const float*)d_in[0];
    const float* hw = (const float*)d_in[1];
    const void* rn = d_in[2];
    const float* bias = (const float*)d_in[3];
    float* out = (float*)d_out;

    const size_t wt_bytes = (size_t)N_DIM * K_DIM * 2;   // 32 MB
    const size_t xb_bytes = (size_t)M_DIM * K_DIM * 2;   // 64 MB
    const size_t tb_bytes = (size_t)(HASH_MASK + 1) * 2; // 2 MB

    if (ws_size >= wt_bytes + xb_bytes + tb_bytes) {
        unsigned short* Wt = (unsigned short*)d_ws;
        unsigned short* Xb = (unsigned short*)((char*)d_ws + wt_bytes);
        unsigned short* Tb = (unsigned short*)((char*)d_ws + wt_bytes + xb_bytes);
        cvt_tbl<<<512, 256, 0, stream>>>(hw, Tb);
        prep_bf<<<16384, 256, 0, stream>>>(x, Tb, rn, Wt, Xb);
        gemm_bt8<<<dim3((M_DIM / 256) * (N_DIM / 256)), 512, 0, stream>>>(Xb, Wt, bias, out);
    } else if (ws_size >= wt_bytes + xb_bytes) {
        unsigned short* Wt = (unsigned short*)d_ws;
        unsigned short* Xb = (unsigned short*)((char*)d_ws + wt_bytes);
        prep_f32<<<16384, 256, 0, stream>>>(x, hw, rn, Wt, Xb);
        gemm_bt8<<<dim3((M_DIM / 256) * (N_DIM / 256)), 512, 0, stream>>>(Xb, Wt, bias, out);
    } else {
        gemm_fused<<<dim3(N_DIM / 128, M_DIM / 128), 256, 0, stream>>>(x, hw, rn, bias, out);
    }
}